// Round 2
// baseline (11150.191 us; speedup 1.0000x reference)
//
#include <hip/hip_runtime.h>

#define Bb 128
#define Tt 512
#define Vv 96
#define Hh 512
#define G4v 2048
#define NBLK 194
#define NTHR 256
#define NSTEP 518
#define OUT_H 6291456
#define OUT_C 6488064

typedef _Float16 f16x4 __attribute__((ext_vector_type(4)));
typedef _Float16 f16x8 __attribute__((ext_vector_type(8)));
typedef float f32x4 __attribute__((ext_vector_type(4)));

struct KP {
  const float *x, *h0, *c0;
  const float *Wih0, *Whh0, *bih0, *bhh0;
  const float *Wih1, *Whh1, *bih1, *bhh1;
  const float *Wih2, *Whh2, *bih2, *bhh2;
  const float *Wfc, *bfc;
  float* out;
  float* fbias;      // [3*2048 + 96] fused biases (b_ih+b_hh per layer; b_fc)
  _Float16* wimg;    // [194][32768] per-block pre-swizzled LDS images
  float* xg;         // [3][4][Bb][G4v]
  _Float16* xb;      // [Bb][Tt][Vv]
  _Float16* ring;    // [3][4][Bb][Hh]
  float* cbuf;       // [3][Bb][Hh]
};

__device__ __forceinline__ float sigf(float x) { return 1.f / (1.f + __expf(-x)); }

// [128 x NF*16] += A[128 x K] * W^T, W rows in LDS ([64][LSTRIDE] f16, optional XOR swizzle).
// Waves split M: wave w owns rows w*32..w*32+31 (2 m-frags), all NF n-frags.
// mfma_f32_16x16x16_f16: A row=lane&15, k=(lane>>4)*4+i; D col=lane&15, row=(lane>>4)*4+q.
template <int KSTEPS, int LSTRIDE, bool SWZ, int NF>
__device__ __forceinline__ void gemm_tile(const _Float16* __restrict__ Abase, int astride,
                                          const _Float16* lds, f32x4 (&acc)[2][NF]) {
  const int lane = threadIdx.x & 63;
  const int w = threadIdx.x >> 6;
  const int l15 = lane & 15, l4 = lane >> 4;
  const _Float16* a0p = Abase + (w * 32 + l15) * astride + l4 * 4;
  const _Float16* a1p = a0p + 16 * astride;
#pragma unroll 4
  for (int ks = 0; ks < KSTEPS; ++ks) {
    const int kk = ks * 16;
    f16x4 av0 = *(const f16x4*)(a0p + kk);
    f16x4 av1 = *(const f16x4*)(a1p + kk);
#pragma unroll
    for (int n = 0; n < NF; ++n) {
      const int r = n * 16 + l15;
      int idx = r * LSTRIDE + kk + l4 * 4;
      if (SWZ) idx ^= (r & 7) << 3;
      f16x4 bv = *(const f16x4*)(lds + idx);
      acc[0][n] = __builtin_amdgcn_mfma_f32_16x16x16f16(av0, bv, acc[0][n], 0, 0, 0);
      acc[1][n] = __builtin_amdgcn_mfma_f32_16x16x16f16(av1, bv, acc[1][n], 0, 0, 0);
    }
  }
}

__global__ __launch_bounds__(NTHR) void prologue_kernel(KP A) {
  const int tid = threadIdx.x, bid = blockIdx.x;
  const int gt = bid * NTHR + tid, gn = NBLK * NTHR;
  for (int i = gt; i < Bb * Tt * Vv; i += gn) A.xb[i] = (_Float16)A.x[i];
  for (int i = gt; i < 3 * Bb * Hh; i += gn) {
    int l = i >> 16, rem = i & 65535;
    A.ring[(l * 4 + 3) * (Bb * Hh) + rem] = (_Float16)A.h0[i];
    A.cbuf[i] = A.c0[i];
  }
  for (int i = gt; i < 3 * G4v; i += gn) {
    int l = i >> 11, c = i & 2047;
    const float* bi = (l == 0) ? A.bih0 : (l == 1) ? A.bih1 : A.bih2;
    const float* bh = (l == 0) ? A.bhh0 : (l == 1) ? A.bhh1 : A.bhh2;
    A.fbias[i] = bi[c] + bh[c];
  }
  for (int i = gt; i < Vv; i += gn) A.fbias[3 * G4v + i] = A.bfc[i];

  // per-block weight image (fp32 -> f16, swizzle baked in)
  _Float16* img = A.wimg + bid * 32768;
  if (bid < 96) {
    int rl = bid / 32, nt = bid % 32;
    const float* Wi = (rl == 0) ? A.Wih0 : (rl == 1) ? A.Wih1 : A.Wih2;
    const int K = (rl == 0) ? Vv : Hh;
    for (int e = tid; e < 64 * K; e += NTHR) {
      int r = e / K, k = e - r * K;
      float v = Wi[(nt * 64 + r) * K + k];
      int idx = (rl == 0) ? (r * 104 + k) : ((r * 512 + k) ^ ((r & 7) << 3));
      img[idx] = (_Float16)v;
    }
  } else if (bid < 192) {
    int rl = (bid - 96) / 32, j0 = ((bid - 96) % 32) * 16;
    const float* Wh = (rl == 0) ? A.Whh0 : (rl == 1) ? A.Whh1 : A.Whh2;
    for (int e = tid; e < 64 * 512; e += NTHR) {
      int r = e >> 9, k = e & 511;
      float v = Wh[((r >> 4) * 512 + j0 + (r & 15)) * Hh + k];
      img[(r * 512 + k) ^ ((r & 7) << 3)] = (_Float16)v;
    }
  } else {
    int nt = bid - 192;
    for (int e = tid; e < 48 * 512; e += NTHR) {
      int r = e >> 9, k = e & 511;
      img[(r * 512 + k) ^ ((r & 7) << 3)] = (_Float16)A.Wfc[(nt * 48 + r) * Hh + k];
    }
  }
}

__global__ __launch_bounds__(NTHR) void step_kernel(KP A, int s) {
  __shared__ _Float16 wlds[32768];
  const int tid = threadIdx.x, bid = blockIdx.x;
  const int lane = tid & 63, w = tid >> 6;
  const int l15 = lane & 15, l4 = lane >> 4;

  int role, rl = 0, nt = 0, j0 = 0, t;
  if (bid < 96)       { role = 0; rl = bid / 32; nt = bid % 32; t = s - 2 * rl; }
  else if (bid < 192) { role = 1; rl = (bid - 96) / 32; j0 = ((bid - 96) % 32) * 16; t = s - 2 * rl - 1; }
  else                { role = 2; nt = bid - 192; t = s - 6; }
  if (t < 0 || t >= Tt) return;

  {  // stage pre-baked image: linear coalesced 16B copies (swizzle already baked in)
    const f16x8* src = (const f16x8*)(A.wimg + bid * 32768);
    f16x8* dst = (f16x8*)wlds;
    for (int e = tid; e < 4096; e += NTHR) dst[e] = src[e];
  }
  __syncthreads();

  if (role == 0) {
    f32x4 acc[2][4] = {};
    if (rl == 0) gemm_tile<6, 104, false, 4>(A.xb + t * Vv, Tt * Vv, wlds, acc);
    else         gemm_tile<32, 512, true, 4>(A.ring + ((rl - 1) * 4 + (t & 3)) * (Bb * Hh), Hh, wlds, acc);
    float biasr[4];
#pragma unroll
    for (int n = 0; n < 4; ++n) biasr[n] = A.fbias[rl * G4v + nt * 64 + n * 16 + l15];
    float* xgp = A.xg + (rl * 4 + (t & 3)) * (Bb * G4v) + nt * 64;
#pragma unroll
    for (int m = 0; m < 2; ++m)
#pragma unroll
      for (int n = 0; n < 4; ++n)
#pragma unroll
        for (int q = 0; q < 4; ++q) {
          int b = w * 32 + m * 16 + l4 * 4 + q;
          xgp[b * G4v + n * 16 + l15] = acc[m][n][q] + biasr[n];
        }
  } else if (role == 1) {
    f32x4 acc[2][4] = {};
    gemm_tile<32, 512, true, 4>(A.ring + (rl * 4 + ((t - 1) & 3)) * (Bb * Hh), Hh, wlds, acc);
    const float* xgp = A.xg + (rl * 4 + (t & 3)) * (Bb * G4v);
    _Float16* rp = A.ring + (rl * 4 + (t & 3)) * (Bb * Hh);
    float* cp = A.cbuf + rl * (Bb * Hh);
    const int j = j0 + l15;
#pragma unroll
    for (int m = 0; m < 2; ++m)
#pragma unroll
      for (int q = 0; q < 4; ++q) {
        const int b = w * 32 + m * 16 + l4 * 4 + q;
        float gi = acc[m][0][q] + xgp[b * G4v + 0 * Hh + j];
        float gf = acc[m][1][q] + xgp[b * G4v + 1 * Hh + j];
        float gg = acc[m][2][q] + xgp[b * G4v + 2 * Hh + j];
        float go = acc[m][3][q] + xgp[b * G4v + 3 * Hh + j];
        float iv = sigf(gi), fv = sigf(gf), gv = tanhf(gg), ov = sigf(go);
        float cold = cp[b * Hh + j];
        float cn = fv * cold + iv * gv;
        cp[b * Hh + j] = cn;
        float hv = ov * tanhf(cn);
        rp[b * Hh + j] = (_Float16)hv;
        if (t == Tt - 1) {
          A.out[OUT_H + (rl * Bb + b) * Hh + j] = hv;
          A.out[OUT_C + (rl * Bb + b) * Hh + j] = cn;
        }
      }
  } else {
    f32x4 acc[2][3] = {};
    gemm_tile<32, 512, true, 3>(A.ring + (8 + (t & 3)) * (Bb * Hh), Hh, wlds, acc);
    float biasr[3];
#pragma unroll
    for (int n = 0; n < 3; ++n) biasr[n] = A.fbias[3 * G4v + nt * 48 + n * 16 + l15];
#pragma unroll
    for (int m = 0; m < 2; ++m)
#pragma unroll
      for (int n = 0; n < 3; ++n)
#pragma unroll
        for (int q = 0; q < 4; ++q) {
          int b = w * 32 + m * 16 + l4 * 4 + q;
          A.out[(b * Tt + t) * Vv + nt * 48 + n * 16 + l15] = acc[m][n][q] + biasr[n];
        }
  }
}

extern "C" void kernel_launch(void* const* d_in, const int* in_sizes, int n_in,
                              void* d_out, int out_size, void* d_ws, size_t ws_size,
                              hipStream_t stream) {
  char* base = (char*)d_ws;
  KP a;
  a.x    = (const float*)d_in[0];
  a.h0   = (const float*)d_in[1];
  a.c0   = (const float*)d_in[2];
  a.Wih0 = (const float*)d_in[3];  a.Whh0 = (const float*)d_in[4];
  a.bih0 = (const float*)d_in[5];  a.bhh0 = (const float*)d_in[6];
  a.Wih1 = (const float*)d_in[7];  a.Whh1 = (const float*)d_in[8];
  a.bih1 = (const float*)d_in[9];  a.bhh1 = (const float*)d_in[10];
  a.Wih2 = (const float*)d_in[11]; a.Whh2 = (const float*)d_in[12];
  a.bih2 = (const float*)d_in[13]; a.bhh2 = (const float*)d_in[14];
  a.Wfc  = (const float*)d_in[15]; a.bfc  = (const float*)d_in[16];
  a.out  = (float*)d_out;
  a.fbias = (float*)base;                       // 25,600 B reserved
  a.wimg  = (_Float16*)(base + 25600);          // 12,713,984 B
  a.xg    = (float*)(base + 12739584);          // 12,582,912 B
  a.xb    = (_Float16*)(base + 25322496);       // 12,582,912 B
  a.ring  = (_Float16*)(base + 37905408);       // 1,572,864 B
  a.cbuf  = (float*)(base + 39478272);          // 786,432 B   (total ~40.3 MB)

  hipLaunchKernelGGL(prologue_kernel, dim3(NBLK), dim3(NTHR), 0, stream, a);
  for (int s = 0; s < NSTEP; ++s)
    hipLaunchKernelGGL(step_kernel, dim3(NBLK), dim3(NTHR), 0, stream, a, s);
}